// Round 12
// baseline (785.053 us; speedup 1.0000x reference)
//
#include <hip/hip_runtime.h>
#include <hip/hip_cooperative_groups.h>
#include <math.h>

namespace cg = cooperative_groups;

#define FDIM 128
#define AVG_D_LOGF 2.6f
#define BN_EPS 1e-5f
#define NK 10          // gemm K-steps: 2 (h section) + 8 (agg section)

using f32x2 = __attribute__((ext_vector_type(2))) float;
using f32x4 = __attribute__((ext_vector_type(4))) float;
using s16x8 = __attribute__((ext_vector_type(8))) short;
using u16x8 = __attribute__((ext_vector_type(8))) unsigned short;

__device__ __forceinline__ unsigned short f2bf(float x) {
  unsigned int u = __float_as_uint(x);
  u += 0x7FFFu + ((u >> 16) & 1u);   // RNE; inputs are finite
  return (unsigned short)(u >> 16);
}
__device__ __forceinline__ f32x2 bfpair(unsigned int u) {
  union { uint2 u2; f32x2 f; } c;
  c.u2 = make_uint2(u << 16, u & 0xFFFF0000u);
  return c.f;
}
__device__ __forceinline__ void gload16(const void* g, void* l) {
  __builtin_amdgcn_global_load_lds(
      (const __attribute__((address_space(1))) void*)g,
      (__attribute__((address_space(3))) void*)l, 16, 0, 0);
}

// ================= K1: zero + prep + scan + csr_fill + agg =================
struct P1 {
  const float* h; const int* src; const int* dst; const float* W;
  unsigned short* hb; unsigned short* wBT;
  int* deg; int* cursor; float* bnsum; float* bnsq;
  int* offs; int* bsums; int* exg; int* csr;
  unsigned short* aggb; float2* s12a;
  int n, E, K, nb, w0, w1, w2;
};

__global__ __launch_bounds__(256, 8) void k1_fused(P1 p) {
  cg::grid_group gg = cg::this_grid();
  __shared__ int tmp[256];
  const int t = threadIdx.x;
  const int gtid = blockIdx.x * 256 + t;
  const int gsz = gridDim.x * 256;

  // ---- phase 0: zero scratch ----
  for (int i = gtid; i < p.n; i += gsz) { p.deg[i] = 0; p.cursor[i] = 0; }
  if (gtid < 128) { p.bnsum[gtid] = 0.f; p.bnsq[gtid] = 0.f; }
  gg.sync();

  // ---- phase 1: h->bf16, W->bf16^T, degree count ----
  const int wtot = p.w0 + p.w1 + p.w2;
  for (int i = gtid; i < wtot; i += gsz) {
    if (i < p.w0) {
      const f32x4* sp = (const f32x4*)p.h + (size_t)i * 2;
      f32x4 v0 = sp[0], v1 = sp[1];
      u16x8 o;
      o[0] = f2bf(v0[0]); o[1] = f2bf(v0[1]); o[2] = f2bf(v0[2]); o[3] = f2bf(v0[3]);
      o[4] = f2bf(v1[0]); o[5] = f2bf(v1[1]); o[6] = f2bf(v1[2]); o[7] = f2bf(v1[3]);
      *((u16x8*)p.hb + i) = o;
    } else if (i < p.w0 + p.w1) {
      int idx = i - p.w0;
      int k = idx >> 7, j = idx & 127;
      p.wBT[(size_t)j * p.K + k] = f2bf(p.W[idx]);
    } else {
      atomicAdd(&p.deg[p.dst[i - p.w0 - p.w1]], 1);
    }
  }
  gg.sync();

  // ---- phase 2: block-local exclusive scan of deg (256-node segments) ----
  for (int b = blockIdx.x; b < p.nb; b += gridDim.x) {
    int i = b * 256 + t;
    int v = (i < p.n) ? p.deg[i] : 0;
    tmp[t] = v; __syncthreads();
    for (int d = 1; d < 256; d <<= 1) {
      int x = (t >= d) ? tmp[t - d] : 0;
      __syncthreads();
      tmp[t] += x;
      __syncthreads();
    }
    if (i < p.n) p.offs[i] = tmp[t] - v;
    if (t == 255) p.bsums[b] = tmp[255];
    __syncthreads();
  }
  gg.sync();

  // ---- phase 3: exclusive prefix of segment sums (block 0) ----
  if (blockIdx.x == 0) {
    int v = (t < p.nb) ? p.bsums[t] : 0;
    tmp[t] = v; __syncthreads();
    for (int d = 1; d < 256; d <<= 1) {
      int x = (t >= d) ? tmp[t - d] : 0;
      __syncthreads();
      tmp[t] += x;
      __syncthreads();
    }
    if (t < p.nb) p.exg[t] = tmp[t] - v;
  }
  gg.sync();

  // ---- phase 4: csr fill (pre-scaled byte offsets) ----
  for (int i = gtid; i < p.E; i += gsz) {
    int d = p.dst[i];
    int pos = p.offs[d] + p.exg[d >> 8] + atomicAdd(&p.cursor[d], 1);
    p.csr[pos] = p.src[i] << 8;        // byte offset of 256B bf16 row
  }
  gg.sync();

  // ---- phase 5: per-node aggregation (one wave/node, 2 edge-streams, 8B/lane) ----
  const int lane = t & 63;
  const int wid0 = gtid >> 6;
  const int nwav = gsz >> 6;
  const int sub = lane >> 5;
  const int fl  = lane & 31;
  const char* hbase = (const char*)p.hb + fl * 8;

  for (int gw = wid0; gw < p.n; gw += nwav) {
    const int beg = p.offs[gw] + p.exg[gw >> 8];
    const int end = (gw + 1 < p.n) ? p.offs[gw + 1] + p.exg[(gw + 1) >> 8] : p.E;

    f32x2 s0v = {0.f, 0.f}, s1v = {0.f, 0.f};
    f32x2 q0v = {0.f, 0.f}, q1v = {0.f, 0.f};
    f32x2 mx0 = {-INFINITY, -INFINITY}, mx1 = {-INFINITY, -INFINITY};
    f32x2 mn0 = {INFINITY, INFINITY},  mn1 = {INFINITY, INFINITY};

    auto acc1 = [&](uint2 A) {
      f32x2 a0 = bfpair(A.x), a1 = bfpair(A.y);
      s0v += a0; s1v += a1;
      q0v += a0 * a0; q1v += a1 * a1;
      mx0[0] = fmaxf(mx0[0], a0[0]); mx0[1] = fmaxf(mx0[1], a0[1]);
      mx1[0] = fmaxf(mx1[0], a1[0]); mx1[1] = fmaxf(mx1[1], a1[1]);
      mn0[0] = fminf(mn0[0], a0[0]); mn0[1] = fminf(mn0[1], a0[1]);
      mn1[0] = fminf(mn1[0], a1[0]); mn1[1] = fminf(mn1[1], a1[1]);
    };
    auto gat = [&](int byteoff) -> uint2 {
      return *(const uint2*)(hbase + byteoff);
    };

    const int cnt = end - beg;
    const int pairs = cnt >> 1;
    int pp = 0;
    for (; pp + 4 <= pairs; pp += 4) {
      int base = beg + 2 * pp + sub;
      int i0 = p.csr[base], i1 = p.csr[base + 2], i2 = p.csr[base + 4], i3 = p.csr[base + 6];
      uint2 A = gat(i0), B = gat(i1), C = gat(i2), D = gat(i3);
      acc1(A); acc1(B); acc1(C); acc1(D);
    }
    for (; pp < pairs; ++pp) acc1(gat(p.csr[beg + 2 * pp + sub]));
    if ((cnt & 1) && sub == 0) acc1(gat(p.csr[end - 1]));

    // merge the two edge-streams (lane ^ 32)
    s0v[0] += __shfl_xor(s0v[0], 32); s0v[1] += __shfl_xor(s0v[1], 32);
    s1v[0] += __shfl_xor(s1v[0], 32); s1v[1] += __shfl_xor(s1v[1], 32);
    q0v[0] += __shfl_xor(q0v[0], 32); q0v[1] += __shfl_xor(q0v[1], 32);
    q1v[0] += __shfl_xor(q1v[0], 32); q1v[1] += __shfl_xor(q1v[1], 32);
    mx0[0] = fmaxf(mx0[0], __shfl_xor(mx0[0], 32)); mx0[1] = fmaxf(mx0[1], __shfl_xor(mx0[1], 32));
    mx1[0] = fmaxf(mx1[0], __shfl_xor(mx1[0], 32)); mx1[1] = fmaxf(mx1[1], __shfl_xor(mx1[1], 32));
    mn0[0] = fminf(mn0[0], __shfl_xor(mn0[0], 32)); mn0[1] = fminf(mn0[1], __shfl_xor(mn0[1], 32));
    mn1[0] = fminf(mn1[0], __shfl_xor(mn1[0], 32)); mn1[1] = fminf(mn1[1], __shfl_xor(mn1[1], 32));

    float degf = (float)cnt;
    if (degf < 1.f) degf = 1.f;
    const float inv = 1.f / degf;
    if (sub == 0) {
      float me0 = s0v[0] * inv, me1 = s0v[1] * inv, me2 = s1v[0] * inv, me3 = s1v[1] * inv;
      float st0 = sqrtf(fmaxf(q0v[0] * inv - me0 * me0, 0.f) + BN_EPS);
      float st1 = sqrtf(fmaxf(q0v[1] * inv - me1 * me1, 0.f) + BN_EPS);
      float st2 = sqrtf(fmaxf(q1v[0] * inv - me2 * me2, 0.f) + BN_EPS);
      float st3 = sqrtf(fmaxf(q1v[1] * inv - me3 * me3, 0.f) + BN_EPS);
      unsigned int b = (unsigned int)gw * 512u + (unsigned int)fl * 4u;
      uint2 wme = make_uint2((unsigned int)f2bf(me0) | ((unsigned int)f2bf(me1) << 16),
                             (unsigned int)f2bf(me2) | ((unsigned int)f2bf(me3) << 16));
      uint2 wmx = make_uint2((unsigned int)f2bf(mx0[0]) | ((unsigned int)f2bf(mx0[1]) << 16),
                             (unsigned int)f2bf(mx1[0]) | ((unsigned int)f2bf(mx1[1]) << 16));
      uint2 wmn = make_uint2((unsigned int)f2bf(mn0[0]) | ((unsigned int)f2bf(mn0[1]) << 16),
                             (unsigned int)f2bf(mn1[0]) | ((unsigned int)f2bf(mn1[1]) << 16));
      uint2 wst = make_uint2((unsigned int)f2bf(st0) | ((unsigned int)f2bf(st1) << 16),
                             (unsigned int)f2bf(st2) | ((unsigned int)f2bf(st3) << 16));
      *(uint2*)&p.aggb[b      ] = wme;
      *(uint2*)&p.aggb[b + 128] = wmx;
      *(uint2*)&p.aggb[b + 256] = wmn;
      *(uint2*)&p.aggb[b + 384] = wst;
    }
    if (lane == 0) {
      float logd = logf(degf + 1.f);
      p.s12a[gw] = make_float2(logd / AVG_D_LOGF, AVG_D_LOGF / logd);
    }
  }
}

// ================= K2: gemm tiles + BN apply =================
struct P2 {
  const unsigned short* hb; const unsigned short* wBT; const unsigned short* aggb;
  const float2* s12a; const float* bias; const float* gamma; const float* beta;
  float* out; float* bnsum; float* bnsq;
  int n, K, ntiles;
};

__global__ __launch_bounds__(256, 3) void k2_fused(P2 p) {
  cg::grid_group gg = cg::this_grid();
  __shared__ s16x8 As[1024];      // 16 KB
  __shared__ s16x8 Bs[3][512];    // 24 KB
  const int t = threadIdx.x;
  const int lane = t & 63;
  const int w = t >> 6;
  const int wr = w >> 1, wc = w & 1;
  const int hi = lane >> 4, lr = lane & 15, rx7 = lr & 7;

  for (int tile = blockIdx.x; tile < p.ntiles; tile += gridDim.x) {
    // bijective XCD-chunked swizzle (m204) over tile space
    const int nwg = p.ntiles;
    const int q = nwg >> 3, r = nwg & 7;
    const int xcd = tile & 7, jj = tile >> 3;
    const int bx = (xcd < r ? xcd * (q + 1) : r * (q + 1) + (xcd - r) * q) + jj;

    const int m0 = (bx >> 1) * 128;
    const int n0 = (bx & 1) * 64;

    f32x4 acc[3][4][2] = {};

    auto stage = [&](int ss) {
      const bool ph1 = (ss < 2);
      #pragma unroll
      for (int i = 0; i < 4; ++i) {
        int unit = w * 256 + i * 64 + lane;
        int row = unit >> 3, x = unit & 7;
        int node = m0 + row; if (node >= p.n) node = p.n - 1;
        int xo = (x ^ (row & 7)) << 3;
        const unsigned short* srcp = ph1
            ? p.hb   + (size_t)node * FDIM + ss * 64 + xo
            : p.aggb + (size_t)node * 512 + (ss - 2) * 64 + xo;
        gload16(srcp, &As[w * 256 + i * 64]);
      }
      const int nsec = ph1 ? 1 : 3;
      for (int s = 0; s < nsec; ++s) {
        int koff = ph1 ? ss * 64 : (FDIM + s * 512 + (ss - 2) * 64);
        #pragma unroll
        for (int i = 0; i < 2; ++i) {
          int unit = w * 128 + i * 64 + lane;
          int row = unit >> 3, x = unit & 7;
          const unsigned short* srcp =
              p.wBT + (size_t)(n0 + row) * p.K + koff + ((x ^ (row & 7)) << 3);
          gload16(srcp, &Bs[s][w * 128 + i * 64]);
        }
      }
    };

    for (int step = 0; step < NK; ++step) {
      stage(step);
      __syncthreads();
      #pragma unroll
      for (int ks = 0; ks < 2; ++ks) {
        s16x8 a[4];
        #pragma unroll
        for (int m = 0; m < 4; ++m) {
          int row = wr * 64 + m * 16 + lr;
          a[m] = As[row * 8 + ((ks * 4 + hi) ^ rx7)];
        }
        #pragma unroll
        for (int s = 0; s < 3; ++s) {
          if (step < 2 && s > 0) continue;    // h section touches only acc[0]
          int rb = wc * 32 + lr;
          s16x8 b0 = Bs[s][rb * 8 + ((ks * 4 + hi) ^ rx7)];
          s16x8 b1 = Bs[s][(rb + 16) * 8 + ((ks * 4 + hi) ^ rx7)];
          #pragma unroll
          for (int m = 0; m < 4; ++m) {
            acc[s][m][0] = __builtin_amdgcn_mfma_f32_16x16x32_bf16(a[m], b0, acc[s][m][0], 0, 0, 0);
            acc[s][m][1] = __builtin_amdgcn_mfma_f32_16x16x32_bf16(a[m], b1, acc[s][m][1], 0, 0, 0);
          }
        }
      }
      __syncthreads();
    }

    // epilogue: combine, bias, relu, store; fused BN partial sums
    float* red = (float*)&As[0];
    if (t < 128) red[t] = 0.f;
    __syncthreads();

    const float bv0 = p.bias[n0 + wc * 32 + lr];
    const float bv1 = p.bias[n0 + wc * 32 + 16 + lr];
    float cs[2] = {0.f, 0.f}, cq[2] = {0.f, 0.f};
    #pragma unroll
    for (int m = 0; m < 4; ++m) {
      #pragma unroll
      for (int i = 0; i < 4; ++i) {
        int grow = m0 + wr * 64 + m * 16 + hi * 4 + i;
        if (grow >= p.n) continue;
        float2 sv = p.s12a[grow];
        #pragma unroll
        for (int nn = 0; nn < 2; ++nn) {
          float v = acc[0][m][nn][i] + sv.x * acc[1][m][nn][i] + sv.y * acc[2][m][nn][i]
                  + (nn ? bv1 : bv0);
          v = fmaxf(v, 0.f);
          p.out[(size_t)grow * FDIM + n0 + wc * 32 + nn * 16 + lr] = v;
          cs[nn] += v; cq[nn] += v * v;
        }
      }
    }
    #pragma unroll
    for (int nn = 0; nn < 2; ++nn) {
      int lc = wc * 32 + nn * 16 + lr;
      atomicAdd(&red[lc], cs[nn]);
      atomicAdd(&red[64 + lc], cq[nn]);
    }
    __syncthreads();
    if (t < 64)       atomicAdd(&p.bnsum[n0 + t], red[t]);
    else if (t < 128) atomicAdd(&p.bnsq[n0 + t - 64], red[t]);
    __syncthreads();   // red region reused by next tile's stage
  }
  gg.sync();

  // ---- BN apply ----
  float* scs = (float*)&As[0];
  float* shs = scs + 128;
  if (t < 128) {
    const float invN = 1.f / (float)p.n;
    const float mu = p.bnsum[t] * invN;
    const float var = p.bnsq[t] * invN - mu * mu;
    const float rs = rsqrtf(var + BN_EPS);
    const float s = p.gamma[t] * rs;
    scs[t] = s; shs[t] = p.beta[t] - mu * s;
  }
  __syncthreads();
  const int total = p.n * 32;            // f32x4 units
  const int gsz = gridDim.x * 256;       // divisible by 32 -> c4 loop-invariant
  int idx = blockIdx.x * 256 + t;
  const int c4 = (idx & 31) * 4;
  const float s0 = scs[c4], s1 = scs[c4 + 1], s2 = scs[c4 + 2], s3 = scs[c4 + 3];
  const float h0 = shs[c4], h1 = shs[c4 + 1], h2 = shs[c4 + 2], h3 = shs[c4 + 3];
  for (; idx < total; idx += gsz) {
    f32x4 v = ((f32x4*)p.out)[idx];
    v[0] = v[0] * s0 + h0;
    v[1] = v[1] * s1 + h1;
    v[2] = v[2] * s2 + h2;
    v[3] = v[3] * s3 + h3;
    ((f32x4*)p.out)[idx] = v;
  }
}

extern "C" void kernel_launch(void* const* d_in, const int* in_sizes, int n_in,
                              void* d_out, int out_size, void* d_ws, size_t ws_size,
                              hipStream_t stream) {
  const float* h     = (const float*)d_in[0];
  const int*   src   = (const int*)d_in[1];
  const int*   dst   = (const int*)d_in[2];
  const float* W     = (const float*)d_in[3];
  const float* bias  = (const float*)d_in[4];
  const float* gamma = (const float*)d_in[5];
  const float* beta  = (const float*)d_in[6];
  float* out = (float*)d_out;

  const int n = in_sizes[0] / FDIM;      // 50000
  const int E = in_sizes[1];             // 650000
  const int K = in_sizes[3] / FDIM;      // 1664

  char* base = (char*)d_ws;
  size_t off = 0;
  auto alloc = [&](size_t bytes) -> void* {
    void* p = base + off;
    off += (bytes + 255) & ~(size_t)255;
    return p;
  };
  int*   deg    = (int*)  alloc(4ull * n);
  int*   cursor = (int*)  alloc(4ull * n);
  float* bnsum  = (float*)alloc(512);
  float* bnsq   = (float*)alloc(512);
  int*    offs  = (int*)  alloc(4ull * (n + 1));
  int*    bsums = (int*)  alloc(4ull * 256);
  int*    exg   = (int*)  alloc(4ull * 256);
  int*    csr   = (int*)  alloc(4ull * E);
  float2* s12a  = (float2*)alloc(8ull * n);
  unsigned short* aggb = (unsigned short*)alloc(2ull * (size_t)n * 512);
  unsigned short* wBT  = (unsigned short*)alloc(2ull * (size_t)K * FDIM);
  unsigned short* hb   = (unsigned short*)alloc(2ull * (size_t)n * FDIM);
  (void)ws_size; (void)n_in; (void)out_size;

  const int nb = (n + 255) / 256;        // 196 segments (<=256)
  const int w0 = n * FDIM / 8;
  const int w1 = K * FDIM;
  const int w2 = E;
  const int ntiles = ((n + 127) / 128) * 2;   // 782

  P1 p1 = { h, src, dst, W, hb, wBT, deg, cursor, bnsum, bnsq,
            offs, bsums, exg, csr, aggb, s12a, n, E, K, nb, w0, w1, w2 };
  P2 p2 = { hb, wBT, aggb, s12a, bias, gamma, beta, out, bnsum, bnsq,
            n, K, ntiles };

  int occ1 = 0, occ2 = 0;
  hipOccupancyMaxActiveBlocksPerMultiprocessor(&occ1, k1_fused, 256, 0);
  hipOccupancyMaxActiveBlocksPerMultiprocessor(&occ2, k2_fused, 256, 0);
  if (occ1 < 1) occ1 = 1;
  if (occ2 < 1) occ2 = 1;
  int grid1 = occ1 * 256; if (grid1 > 2048) grid1 = 2048;
  int grid2 = occ2 * 256; if (grid2 > 1024) grid2 = 1024;

  void* a1[] = { (void*)&p1 };
  void* a2[] = { (void*)&p2 };
  hipLaunchCooperativeKernel(k1_fused, dim3(grid1), dim3(256), a1, 0, stream);
  hipLaunchCooperativeKernel(k2_fused, dim3(grid2), dim3(256), a2, 0, stream);
}

// Round 13
// 174.535 us; speedup vs baseline: 4.4980x; 4.4980x over previous
//
#include <hip/hip_runtime.h>
#include <math.h>

#define FDIM 128
#define AVG_D_LOGF 2.6f
#define BN_EPS 1e-5f
#define NK5 5          // gemm K-steps of BK=128: 1 (h) + 4 (agg)

using f32x2 = __attribute__((ext_vector_type(2))) float;
using f32x4 = __attribute__((ext_vector_type(4))) float;
using s16x8 = __attribute__((ext_vector_type(8))) short;
using u16x8 = __attribute__((ext_vector_type(8))) unsigned short;

__device__ __forceinline__ unsigned short f2bf(float x) {
  unsigned int u = __float_as_uint(x);
  u += 0x7FFFu + ((u >> 16) & 1u);   // RNE; inputs are finite
  return (unsigned short)(u >> 16);
}
__device__ __forceinline__ f32x2 bfpair(unsigned int u) {
  union { uint2 u2; f32x2 f; } c;
  c.u2 = make_uint2(u << 16, u & 0xFFFF0000u);
  return c.f;
}
__device__ __forceinline__ void gload16(const void* g, void* l) {
  __builtin_amdgcn_global_load_lds(
      (const __attribute__((address_space(1))) void*)g,
      (__attribute__((address_space(3))) void*)l, 16, 0, 0);
}

// ---------------- fused prep: h->bf16, W->bf16 transposed, degree count ----------------
__global__ void prep_kernel(const float* __restrict__ h, unsigned short* __restrict__ hb,
                            const float* __restrict__ W, unsigned short* __restrict__ wBT,
                            const int* __restrict__ dst, int* __restrict__ deg,
                            int w0, int w1, int w2, int K) {
  int i = blockIdx.x * 256 + threadIdx.x;
  if (i < w0) {                       // conv_h: 8 elems per thread
    const f32x4* sp = (const f32x4*)h + (size_t)i * 2;
    f32x4 v0 = sp[0], v1 = sp[1];
    u16x8 o;
    o[0] = f2bf(v0[0]); o[1] = f2bf(v0[1]); o[2] = f2bf(v0[2]); o[3] = f2bf(v0[3]);
    o[4] = f2bf(v1[0]); o[5] = f2bf(v1[1]); o[6] = f2bf(v1[2]); o[7] = f2bf(v1[3]);
    *((u16x8*)hb + i) = o;
  } else if (i < w0 + w1) {           // conv_wt: 1 elem per thread
    int idx = i - w0;
    int k = idx >> 7, j = idx & 127;
    wBT[(size_t)j * K + k] = f2bf(W[idx]);
  } else if (i < w0 + w1 + w2) {      // degree count
    atomicAdd(&deg[dst[i - w0 - w1]], 1);
  }
}

// ---------------- CSR build: block-local scan; consumers recompute bsums prefix ----------------
__global__ void scan1(const int* __restrict__ deg, int* __restrict__ offs,
                      int* __restrict__ bsums, int n) {
  __shared__ int tmp[256];
  int t = threadIdx.x, i = blockIdx.x * 256 + t;
  int v = (i < n) ? deg[i] : 0;
  tmp[t] = v; __syncthreads();
  for (int d = 1; d < 256; d <<= 1) {
    int x = (t >= d) ? tmp[t - d] : 0;
    __syncthreads();
    tmp[t] += x;
    __syncthreads();
  }
  if (i < n) offs[i] = tmp[t] - v;
  if (t == 255) bsums[blockIdx.x] = tmp[255];
}

// csr stores PRE-SCALED byte offsets (src * 256) so agg's gather is base+idx.
__global__ void csr_fill(const int* __restrict__ src, const int* __restrict__ dst,
                         const int* __restrict__ offs, const int* __restrict__ bsums,
                         int* __restrict__ cursor, int* __restrict__ csr, int E, int nb) {
  __shared__ int tmp[256];
  __shared__ int ex[256];
  const int t = threadIdx.x;
  {
    int v = (t < nb) ? bsums[t] : 0;
    tmp[t] = v; __syncthreads();
    for (int d = 1; d < 256; d <<= 1) {
      int x = (t >= d) ? tmp[t - d] : 0;
      __syncthreads();
      tmp[t] += x;
      __syncthreads();
    }
    ex[t] = tmp[t] - v;
    __syncthreads();
  }
  int i = blockIdx.x * 256 + t;
  if (i < E) {
    int d = dst[i];
    int pos = offs[d] + ex[d >> 8] + atomicAdd(&cursor[d], 1);
    csr[pos] = src[i] << 8;            // byte offset of 256B bf16 row
  }
}

// ---------------- per-node aggregation: one wave per node, 2 edge-streams,
// uint2 (4 bf16) per lane (r9 structure, measured 53.4us — floor for this pattern).
__global__ __launch_bounds__(256) void agg_kernel(
    const unsigned short* __restrict__ hb, const int* __restrict__ csr,
    const int* __restrict__ offs, const int* __restrict__ bsums,
    unsigned short* __restrict__ aggb, float2* __restrict__ s12a,
    int n, int E, int nb) {
  __shared__ int tmp[256];
  __shared__ int ex[256];
  {
    int t = threadIdx.x;
    int v = (t < nb) ? bsums[t] : 0;
    tmp[t] = v; __syncthreads();
    for (int d = 1; d < 256; d <<= 1) {
      int x = (t >= d) ? tmp[t - d] : 0;
      __syncthreads();
      tmp[t] += x;
      __syncthreads();
    }
    ex[t] = tmp[t] - v;
    __syncthreads();
  }
  const int gw = (blockIdx.x * 256 + threadIdx.x) >> 6;
  const int lane = threadIdx.x & 63;
  if (gw >= n) return;
  const int beg = offs[gw] + ex[gw >> 8];
  const int end = (gw + 1 < n) ? offs[gw + 1] + ex[(gw + 1) >> 8] : E;
  const int sub = lane >> 5;          // which edge of the pair
  const int fl  = lane & 31;          // features 4*fl .. 4*fl+3
  const char* hbase = (const char*)hb + fl * 8;   // loop-invariant lane base

  f32x2 s0v = {0.f, 0.f}, s1v = {0.f, 0.f};
  f32x2 q0v = {0.f, 0.f}, q1v = {0.f, 0.f};
  f32x2 mx0 = {-INFINITY, -INFINITY}, mx1 = {-INFINITY, -INFINITY};
  f32x2 mn0 = {INFINITY, INFINITY},  mn1 = {INFINITY, INFINITY};

  auto acc1 = [&](uint2 A) {
    f32x2 a0 = bfpair(A.x), a1 = bfpair(A.y);
    s0v += a0; s1v += a1;
    q0v += a0 * a0; q1v += a1 * a1;
    mx0[0] = fmaxf(mx0[0], a0[0]); mx0[1] = fmaxf(mx0[1], a0[1]);
    mx1[0] = fmaxf(mx1[0], a1[0]); mx1[1] = fmaxf(mx1[1], a1[1]);
    mn0[0] = fminf(mn0[0], a0[0]); mn0[1] = fminf(mn0[1], a0[1]);
    mn1[0] = fminf(mn1[0], a1[0]); mn1[1] = fminf(mn1[1], a1[1]);
  };
  auto gat = [&](int byteoff) -> uint2 {
    return *(const uint2*)(hbase + byteoff);
  };

  const int cnt = end - beg;
  const int pairs = cnt >> 1;
  int p = 0;
  for (; p + 4 <= pairs; p += 4) {
    int base = beg + 2 * p + sub;
    int i0 = csr[base], i1 = csr[base + 2], i2 = csr[base + 4], i3 = csr[base + 6];
    uint2 A = gat(i0), B = gat(i1), C = gat(i2), D = gat(i3);
    acc1(A); acc1(B); acc1(C); acc1(D);
  }
  for (; p < pairs; ++p) {
    acc1(gat(csr[beg + 2 * p + sub]));
  }
  if ((cnt & 1) && sub == 0) {
    acc1(gat(csr[end - 1]));
  }

  // merge the two edge-streams (lane ^ 32)
  s0v[0] += __shfl_xor(s0v[0], 32); s0v[1] += __shfl_xor(s0v[1], 32);
  s1v[0] += __shfl_xor(s1v[0], 32); s1v[1] += __shfl_xor(s1v[1], 32);
  q0v[0] += __shfl_xor(q0v[0], 32); q0v[1] += __shfl_xor(q0v[1], 32);
  q1v[0] += __shfl_xor(q1v[0], 32); q1v[1] += __shfl_xor(q1v[1], 32);
  mx0[0] = fmaxf(mx0[0], __shfl_xor(mx0[0], 32)); mx0[1] = fmaxf(mx0[1], __shfl_xor(mx0[1], 32));
  mx1[0] = fmaxf(mx1[0], __shfl_xor(mx1[0], 32)); mx1[1] = fmaxf(mx1[1], __shfl_xor(mx1[1], 32));
  mn0[0] = fminf(mn0[0], __shfl_xor(mn0[0], 32)); mn0[1] = fminf(mn0[1], __shfl_xor(mn0[1], 32));
  mn1[0] = fminf(mn1[0], __shfl_xor(mn1[0], 32)); mn1[1] = fminf(mn1[1], __shfl_xor(mn1[1], 32));

  float degf = (float)cnt;
  if (degf < 1.f) degf = 1.f;
  const float inv = 1.f / degf;
  if (sub == 0) {
    float me0 = s0v[0] * inv, me1 = s0v[1] * inv, me2 = s1v[0] * inv, me3 = s1v[1] * inv;
    float st0 = sqrtf(fmaxf(q0v[0] * inv - me0 * me0, 0.f) + BN_EPS);
    float st1 = sqrtf(fmaxf(q0v[1] * inv - me1 * me1, 0.f) + BN_EPS);
    float st2 = sqrtf(fmaxf(q1v[0] * inv - me2 * me2, 0.f) + BN_EPS);
    float st3 = sqrtf(fmaxf(q1v[1] * inv - me3 * me3, 0.f) + BN_EPS);
    unsigned int b = (unsigned int)gw * 512u + (unsigned int)fl * 4u;
    uint2 wme = make_uint2((unsigned int)f2bf(me0) | ((unsigned int)f2bf(me1) << 16),
                           (unsigned int)f2bf(me2) | ((unsigned int)f2bf(me3) << 16));
    uint2 wmx = make_uint2((unsigned int)f2bf(mx0[0]) | ((unsigned int)f2bf(mx0[1]) << 16),
                           (unsigned int)f2bf(mx1[0]) | ((unsigned int)f2bf(mx1[1]) << 16));
    uint2 wmn = make_uint2((unsigned int)f2bf(mn0[0]) | ((unsigned int)f2bf(mn0[1]) << 16),
                           (unsigned int)f2bf(mn1[0]) | ((unsigned int)f2bf(mn1[1]) << 16));
    uint2 wst = make_uint2((unsigned int)f2bf(st0) | ((unsigned int)f2bf(st1) << 16),
                           (unsigned int)f2bf(st2) | ((unsigned int)f2bf(st3) << 16));
    *(uint2*)&aggb[b      ] = wme;
    *(uint2*)&aggb[b + 128] = wmx;
    *(uint2*)&aggb[b + 256] = wmn;
    *(uint2*)&aggb[b + 384] = wst;
  }
  if (lane == 0) {
    float logd = logf(degf + 1.f);
    s12a[gw] = make_float2(logd / AVG_D_LOGF, AVG_D_LOGF / logd);
  }
}

// ---------------- fused GEMM: BK=128, 5 K-steps, single-buffer 80KB LDS,
// gload16 + source XOR swizzle + bijective XCD swizzle. Halves sync events
// vs BK=64 dbuf (r3: 49.2us) and doubles per-phase loads in flight.
// launch_bounds MUST stay (256,2): (256,4) forced VGPR<=64 -> acc spilled (r7).
__global__ __launch_bounds__(256, 2) void gemm_kernel(
    const unsigned short* __restrict__ hb, const unsigned short* __restrict__ wBT,
    const unsigned short* __restrict__ aggb, const float2* __restrict__ s12a,
    const float* __restrict__ bias, float* __restrict__ out,
    float* __restrict__ bnsum, float* __restrict__ bnsq, int n, int K) {
  __shared__ s16x8 As[2048];      // 128 rows x 16 units (16B) = 32 KB
  __shared__ s16x8 Bs[3][1024];   // 3 x 64 rows x 16 units = 48 KB
  const int t = threadIdx.x;
  const int lane = t & 63;
  const int w = t >> 6;
  const int wr = w >> 1, wc = w & 1;
  const int hi = lane >> 4, lr = lane & 15, rx7 = lr & 7;

  // bijective XCD-chunked swizzle (m204)
  const int nwg = gridDim.x;
  const int q = nwg >> 3, r = nwg & 7;
  const int xcd = blockIdx.x & 7, jj = blockIdx.x >> 3;
  const int bx = (xcd < r ? xcd * (q + 1) : r * (q + 1) + (xcd - r) * q) + jj;

  const int m0 = (bx >> 1) * 128;
  const int n0 = (bx & 1) * 64;

  f32x4 acc[3][4][2] = {};

  auto stage = [&](int ss) {              // ss==0: h section; ss>=1: agg step ss-1
    const bool ph1 = (ss == 0);
    // A tile: 128 rows x 128 cols, 32 gloads (8 per wave)
    #pragma unroll
    for (int i = 0; i < 8; ++i) {
      int unit = w * 512 + i * 64 + lane;
      int row = unit >> 4, xf = unit & 15;
      int half = xf >> 3, x = xf & 7;
      int node = m0 + row; if (node >= n) node = n - 1;
      int col = half * 64 + ((x ^ (row & 7)) << 3);
      const unsigned short* src = ph1
          ? hb   + (size_t)node * FDIM + col
          : aggb + (size_t)node * 512 + (ss - 1) * 128 + col;
      gload16(src, &As[w * 512 + i * 64]);
    }
    // B tiles: per section 64 rows x 128 cols, 16 gloads (4 per wave)
    const int nsec = ph1 ? 1 : 3;
    for (int s = 0; s < nsec; ++s) {
      int koff = ph1 ? 0 : (FDIM + s * 512 + (ss - 1) * 128);
      #pragma unroll
      for (int i = 0; i < 4; ++i) {
        int unit = w * 256 + i * 64 + lane;
        int row = unit >> 4, xf = unit & 15;
        int half = xf >> 3, x = xf & 7;
        int col = half * 64 + ((x ^ (row & 7)) << 3);
        const unsigned short* src = wBT + (size_t)(n0 + row) * K + koff + col;
        gload16(src, &Bs[s][w * 256 + i * 64]);
      }
    }
  };

  for (int step = 0; step < NK5; ++step) {
    stage(step);
    __syncthreads();                      // vmcnt(0) drain + barrier
    #pragma unroll
    for (int ks = 0; ks < 4; ++ks) {      // 4 k-slices of 32 within BK=128
      const int uidx = ((ks >> 1) << 3) + ((((ks << 2) + hi) & 7) ^ rx7);
      s16x8 a[4];
      #pragma unroll
      for (int m = 0; m < 4; ++m) {
        int row = wr * 64 + m * 16 + lr;
        a[m] = As[row * 16 + uidx];
      }
      #pragma unroll
      for (int s = 0; s < 3; ++s) {
        if (step == 0 && s > 0) continue;  // h section touches only acc[0]
        int rb = wc * 32 + lr;
        s16x8 b0 = Bs[s][rb * 16 + uidx];
        s16x8 b1 = Bs[s][(rb + 16) * 16 + uidx];
        #pragma unroll
        for (int m = 0; m < 4; ++m) {
          acc[s][m][0] = __builtin_amdgcn_mfma_f32_16x16x32_bf16(a[m], b0, acc[s][m][0], 0, 0, 0);
          acc[s][m][1] = __builtin_amdgcn_mfma_f32_16x16x32_bf16(a[m], b1, acc[s][m][1], 0, 0, 0);
        }
      }
    }
    __syncthreads();                      // LDS free before next stage
  }

  // ---- epilogue: combine, bias, relu, store; fused BN partial sums ----
  float* red = (float*)&As[0];            // 128 floats
  if (t < 128) red[t] = 0.f;
  __syncthreads();

  const float bv0 = bias[n0 + wc * 32 + lr];
  const float bv1 = bias[n0 + wc * 32 + 16 + lr];
  float cs[2] = {0.f, 0.f}, cq[2] = {0.f, 0.f};
  #pragma unroll
  for (int m = 0; m < 4; ++m) {
    #pragma unroll
    for (int i = 0; i < 4; ++i) {
      int grow = m0 + wr * 64 + m * 16 + hi * 4 + i;
      if (grow >= n) continue;
      float2 sv = s12a[grow];
      #pragma unroll
      for (int nn = 0; nn < 2; ++nn) {
        float v = acc[0][m][nn][i] + sv.x * acc[1][m][nn][i] + sv.y * acc[2][m][nn][i]
                + (nn ? bv1 : bv0);
        v = fmaxf(v, 0.f);
        out[(size_t)grow * FDIM + n0 + wc * 32 + nn * 16 + lr] = v;
        cs[nn] += v; cq[nn] += v * v;
      }
    }
  }
  #pragma unroll
  for (int nn = 0; nn < 2; ++nn) {
    int lc = wc * 32 + nn * 16 + lr;
    atomicAdd(&red[lc], cs[nn]);
    atomicAdd(&red[64 + lc], cq[nn]);
  }
  __syncthreads();
  if (t < 64)       atomicAdd(&bnsum[n0 + t], red[t]);
  else if (t < 128) atomicAdd(&bnsq[n0 + t - 64], red[t]);
}

// ---------------- BatchNorm apply (vectorized f32x4) ----------------
__global__ void bn_norm(float* __restrict__ out, const float* __restrict__ bnsum,
                        const float* __restrict__ bnsq, const float* __restrict__ gamma,
                        const float* __restrict__ beta, int n) {
  __shared__ float scs[128], shs[128];
  const int t = threadIdx.x;
  if (t < 128) {
    const float invN = 1.f / (float)n;
    const float mu = bnsum[t] * invN;
    const float var = bnsq[t] * invN - mu * mu;
    const float rs = rsqrtf(var + BN_EPS);
    const float s = gamma[t] * rs;
    scs[t] = s; shs[t] = beta[t] - mu * s;
  }
  __syncthreads();
  const int total = n * 32;            // f32x4 units
  int idx = blockIdx.x * 256 + t;
  const int c4 = (idx & 31) * 4;       // loop-invariant: stride divisible by 32
  const float s0 = scs[c4], s1 = scs[c4 + 1], s2 = scs[c4 + 2], s3 = scs[c4 + 3];
  const float h0 = shs[c4], h1 = shs[c4 + 1], h2 = shs[c4 + 2], h3 = shs[c4 + 3];
  for (; idx < total; idx += gridDim.x * 256) {
    f32x4 v = ((f32x4*)out)[idx];
    v[0] = v[0] * s0 + h0;
    v[1] = v[1] * s1 + h1;
    v[2] = v[2] * s2 + h2;
    v[3] = v[3] * s3 + h3;
    ((f32x4*)out)[idx] = v;
  }
}

extern "C" void kernel_launch(void* const* d_in, const int* in_sizes, int n_in,
                              void* d_out, int out_size, void* d_ws, size_t ws_size,
                              hipStream_t stream) {
  const float* h     = (const float*)d_in[0];
  const int*   src   = (const int*)d_in[1];
  const int*   dst   = (const int*)d_in[2];
  const float* W     = (const float*)d_in[3];
  const float* bias  = (const float*)d_in[4];
  const float* gamma = (const float*)d_in[5];
  const float* beta  = (const float*)d_in[6];
  float* out = (float*)d_out;

  const int n = in_sizes[0] / FDIM;      // 50000
  const int E = in_sizes[1];             // 650000
  const int K = in_sizes[3] / FDIM;      // 1664

  char* base = (char*)d_ws;
  size_t off = 0;
  auto alloc = [&](size_t bytes) -> void* {
    void* p = base + off;
    off += (bytes + 255) & ~(size_t)255;
    return p;
  };
  int*   deg    = (int*)  alloc(4ull * n);
  int*   cursor = (int*)  alloc(4ull * n);
  float* bnsum  = (float*)alloc(512);
  float* bnsq   = (float*)alloc(512);
  const size_t zlen = off;               // zero deg+cursor+bn each call
  int*    offs  = (int*)  alloc(4ull * (n + 1));
  int*    bsums = (int*)  alloc(4ull * 256);
  int*    csr   = (int*)  alloc(4ull * E);
  float2* s12a  = (float2*)alloc(8ull * n);
  unsigned short* aggb = (unsigned short*)alloc(2ull * (size_t)n * 512);
  unsigned short* wBT  = (unsigned short*)alloc(2ull * (size_t)K * FDIM);
  unsigned short* hb   = (unsigned short*)alloc(2ull * (size_t)n * FDIM);
  (void)ws_size; (void)n_in; (void)out_size;

  const int eb = (E + 255) / 256;
  const int nb = (n + 255) / 256;        // 196 scan blocks (<=256)
  const int w0 = n * FDIM / 8;
  const int w1 = K * FDIM;
  const int w2 = E;

  hipMemsetAsync(d_ws, 0, zlen, stream);
  prep_kernel<<<(w0 + w1 + w2 + 255) / 256, 256, 0, stream>>>(h, hb, W, wBT, dst, deg,
                                                              w0, w1, w2, K);
  scan1<<<nb, 256, 0, stream>>>(deg, offs, bsums, n);
  csr_fill<<<eb, 256, 0, stream>>>(src, dst, offs, bsums, cursor, csr, E, nb);
  agg_kernel<<<(n + 3) / 4, 256, 0, stream>>>(hb, csr, offs, bsums, aggb, s12a, n, E, nb);
  const int gblocks = ((n + 127) / 128) * 2;
  gemm_kernel<<<gblocks, 256, 0, stream>>>(hb, wBT, aggb, s12a, bias,
                                           out, bnsum, bnsq, n, K);
  bn_norm<<<2048, 256, 0, stream>>>(out, bnsum, bnsq, gamma, beta, n);
}